// Round 13
// baseline (112.794 us; speedup 1.0000x reference)
//
#include <hip/hip_runtime.h>
#include <math.h>

#define BATCH 4
#define NPTS 8192
#define GS 24                  // 24^3 cells of 0.5 over [-6,6]^3
#define NCP 16384              // padded cells per batch (24^3 = 13824)
#define GMIN (-6.0f)
#define CS 0.5f
#define INVCS 2.0f
#define FINF 3.4e38f
#define QPT 64                 // queries per tile (one per lane)

__device__ __forceinline__ int cellc(float v) {
    int c = (int)((v - GMIN) * INVCS);
    return min(max(c, 0), GS - 1);
}

// branchless sorted top-3 update (R5-proven). Strict '<': incumbent wins ties.
#define INS3(d, idx, E0, E1, E2, I0, I1, I2) do {                     \
    bool c0 = (d) < E0, c1 = (d) < E1, c2 = (d) < E2;                 \
    float n1_ = __builtin_amdgcn_fmed3f(E0, E1, (d));                 \
    float n2_ = __builtin_amdgcn_fmed3f(E1, E2, (d));                 \
    I2 = c1 ? I1 : (c2 ? (idx) : I2);                                 \
    I1 = c0 ? I0 : (c1 ? (idx) : I1);                                 \
    I0 = c0 ? (idx) : I0;                                             \
    E0 = fminf(E0, (d)); E1 = n1_; E2 = n2_;                          \
} while (0)

// shared IDW epilogue: id* are global sorted candidate indices
__device__ __forceinline__ void idw_write(
    float qx, float qy, float qz, int n0, int n1, int n2,
    const float4* __restrict__ ckey, const float4* __restrict__ cflow,
    float* __restrict__ out, int b, int origj)
{
    float wsum = 0.f, f2x = 0.f, f2y = 0.f, f2z = 0.f;
    int idxs[3] = { n0, n1, n2 };
    #pragma unroll
    for (int k = 0; k < 3; ++k) {
        int id = idxs[k];
        float4 c = ckey[id];
        float cx = -0.5f * c.x, cy = -0.5f * c.y, cz = -0.5f * c.z;  // exact
        float dx = cx - qx, dy = cy - qy, dz = cz - qz;
        float dist = sqrtf(fmaf(dx, dx, fmaf(dy, dy, dz * dz)));
        dist = fmaxf(dist, 1e-10f);
        float w = 1.0f / dist;
        wsum += w;
        float4 fl = cflow[id];
        f2x = fmaf(w, fl.x, f2x);
        f2y = fmaf(w, fl.y, f2y);
        f2z = fmaf(w, fl.z, f2z);
    }
    float r = 1.0f / wsum;
    float* ob = out + b * 3 * NPTS;
    ob[origj]            = qx - f2x * r;
    ob[NPTS + origj]     = qy - f2y * r;
    ob[2 * NPTS + origj] = qz - f2z * r;
}

// ---------------------------------------------------------------------------
// K1: histogram candidates AND queries on the same padded grid.
// ---------------------------------------------------------------------------
__global__ __launch_bounds__(256) void bin_both(
    const float* __restrict__ xyz1, const float* __restrict__ xyz2,
    const float* __restrict__ flow1, int* __restrict__ counts_c,
    int* __restrict__ counts_q)
{
    int t = blockIdx.x * 256 + threadIdx.x;       // 2*BATCH*NPTS threads
    if (t < BATCH * NPTS) {
        int b = t >> 13, n = t & (NPTS - 1);
        const float* x = xyz1 + b * 3 * NPTS + n;
        const float* f = flow1 + b * 3 * NPTS + n;
        float wx = x[0] + f[0], wy = x[NPTS] + f[NPTS], wz = x[2*NPTS] + f[2*NPTS];
        int loc = (cellc(wz) * GS + cellc(wy)) * GS + cellc(wx);
        atomicAdd(&counts_c[b * NCP + loc], 1);
    } else {
        int tq = t - BATCH * NPTS;
        int b = tq >> 13, n = tq & (NPTS - 1);
        const float* q = xyz2 + b * 3 * NPTS + n;
        int loc = (cellc(q[2*NPTS]) * GS + cellc(q[NPTS])) * GS + cellc(q[0]);
        atomicAdd(&counts_q[b * NCP + loc], 1);
    }
}

// ---------------------------------------------------------------------------
// K2: exclusive prefix scan via shfl. 8 blocks: 0-3 candidate cells,
// 4-7 query cells; 4 chunks of 4096 each (int4/thread).
// ---------------------------------------------------------------------------
__global__ __launch_bounds__(1024) void scan_chunks(
    const int* __restrict__ cc, int* __restrict__ cs, int* __restrict__ ccur,
    const int* __restrict__ qc, int* __restrict__ qs, int* __restrict__ qcur)
{
    __shared__ int wsum[16];
    __shared__ int wpre[16];
    __shared__ int ctot;
    int blk = blockIdx.x, t = (int)threadIdx.x;
    int lane = t & 63, wid = t >> 6;
    const int* cnts; int* oS; int* oC; int batch;
    if (blk < 4) { batch = blk;     cnts = cc; oS = cs; oC = ccur; }
    else         { batch = blk - 4; cnts = qc; oS = qs; oC = qcur; }
    int base = batch * NCP;
    int carry = batch * NPTS;
    for (int ch = 0; ch < NCP; ch += 4096) {
        int4 v = *(const int4*)&cnts[base + ch + t * 4];
        int tsum = v.x + v.y + v.z + v.w;
        int incl = tsum;
        #pragma unroll
        for (int o = 1; o < 64; o <<= 1) {
            int n = __shfl_up(incl, o);
            if (lane >= o) incl += n;
        }
        if (lane == 63) wsum[wid] = incl;
        __syncthreads();
        if (t < 16) {
            int wv = wsum[t];
            int wincl = wv;
            #pragma unroll
            for (int o = 1; o < 16; o <<= 1) {
                int n = __shfl_up(wincl, o);
                if (t >= o) wincl += n;
            }
            wpre[t] = wincl - wv;
            if (t == 15) ctot = wincl;
        }
        __syncthreads();
        int excl = carry + wpre[wid] + (incl - tsum);
        int4 o4; o4.x = excl; o4.y = excl + v.x; o4.z = o4.y + v.y; o4.w = o4.z + v.z;
        *(int4*)&oS[base + ch + t * 4] = o4;
        *(int4*)&oC[base + ch + t * 4] = o4;
        carry += ctot;
        __syncthreads();
    }
    if (t == 0) oS[base + NCP] = carry;   // sentinel
}

// ---------------------------------------------------------------------------
// K3: scatter candidates (key+flow) AND queries (coords+orig idx) into
// cell-sorted order. One kernel, two halves of the grid.
// ---------------------------------------------------------------------------
__global__ __launch_bounds__(256) void scatter_both(
    const float* __restrict__ xyz1, const float* __restrict__ xyz2,
    const float* __restrict__ flow1, int* __restrict__ ccur,
    int* __restrict__ qcur, float4* __restrict__ ckey,
    float4* __restrict__ cflow, float4* __restrict__ qpos)
{
    int t = blockIdx.x * 256 + threadIdx.x;       // 2*BATCH*NPTS threads
    if (t < BATCH * NPTS) {
        int b = t >> 13, n = t & (NPTS - 1);
        const float* x = xyz1 + b * 3 * NPTS + n;
        const float* f = flow1 + b * 3 * NPTS + n;
        float fx = f[0], fy = f[NPTS], fz = f[2*NPTS];
        float wx = x[0] + fx, wy = x[NPTS] + fy, wz = x[2*NPTS] + fz;
        float nrm = fmaf(wx, wx, fmaf(wy, wy, wz * wz));
        int loc = (cellc(wz) * GS + cellc(wy)) * GS + cellc(wx);
        int pos = atomicAdd(&ccur[b * NCP + loc], 1);
        ckey[pos]  = make_float4(-2.0f*wx, -2.0f*wy, -2.0f*wz, nrm);
        cflow[pos] = make_float4(fx, fy, fz, 0.0f);
    } else {
        int tq = t - BATCH * NPTS;
        int b = tq >> 13, n = tq & (NPTS - 1);
        const float* q = xyz2 + b * 3 * NPTS + n;
        float qx = q[0], qy = q[NPTS], qz = q[2*NPTS];
        int loc = (cellc(qz) * GS + cellc(qy)) * GS + cellc(qx);
        int pos = atomicAdd(&qcur[b * NCP + loc], 1);
        qpos[pos] = make_float4(qx, qy, qz, __int_as_float(n));
    }
}

// ---------------------------------------------------------------------------
// K4: main pass — s_load streaming, no LDS staging, no mid-kernel barriers.
// Block = 512 thr = 8 waves; lane l = query l of the tile's 64 sorted
// queries (every wave holds all 64). Each wave independently recomputes the
// per-slab y/x windows (shfl reduce over its own lanes -> identical across
// waves, keeps the row counter cnt in lockstep) and processes rows where
// (cnt&7)==w. Row point-runs [st,en) are readfirstlane'd to SGPRs so the
// candidate loop index k is wave-uniform -> ckey[k] scalarizes (R7-proven);
// each iteration feeds 64 lane-parallel INS3 updates. One final LDS merge
// of the 8 wave-partials, then per-query margin test (own +-1 cell box,
// grid-edge faces skipped -> exact); unresolved -> compacted fallback list.
// ---------------------------------------------------------------------------
__global__ __launch_bounds__(512) void knn_tile(
    const float4* __restrict__ qpos, const float4* __restrict__ ckey,
    const float4* __restrict__ cflow, const int* __restrict__ cstart,
    int* __restrict__ fbcnt, int* __restrict__ fblist, float* __restrict__ out)
{
    __shared__ float md[8][QPT][3];
    __shared__ int   mi[8][QPT][3];

    int tile = blockIdx.x;               // BATCH*128
    int b = tile >> 7, ti = tile & 127;
    int t = (int)threadIdx.x;
    int w = t >> 6, l = t & 63;
    int qbase = b * NPTS + ti * QPT;

    float4 qp = qpos[qbase + l];
    float qx = qp.x, qy = qp.y, qz = qp.z;
    int origj = __float_as_int(qp.w);
    float qn = fmaf(qx, qx, fmaf(qy, qy, qz * qz));
    int hx = cellc(qx), hy = cellc(qy), hz = cellc(qz);

    int zmn = hz, zmx = hz;
    #pragma unroll
    for (int o = 32; o >= 1; o >>= 1) {
        zmn = min(zmn, __shfl_xor(zmn, o));
        zmx = max(zmx, __shfl_xor(zmx, o));
    }
    int loz = max(zmn - 1, 0), hiz = min(zmx + 1, GS - 1);

    float e0 = FINF, e1 = FINF, e2 = FINF;
    int   i0 = 0, i1 = 0, i2 = 0;
    int cnt = 0;
    int bN = b * NCP;

    for (int z = loz; z <= hiz; ++z) {
        bool act = (hz - z <= 1) && (z - hz <= 1);
        int ymn = act ? hy : 1000, ymx = act ? hy : -1000;
        int xmn = act ? hx : 1000, xmx = act ? hx : -1000;
        #pragma unroll
        for (int o = 32; o >= 1; o >>= 1) {
            ymn = min(ymn, __shfl_xor(ymn, o));
            ymx = max(ymx, __shfl_xor(ymx, o));
            xmn = min(xmn, __shfl_xor(xmn, o));
            xmx = max(xmx, __shfl_xor(xmx, o));
        }
        if (ymn == 1000) continue;                 // no query needs this slab
        int ylo = max(ymn - 1, 0), yhi = min(ymx + 1, GS - 1);
        int xlo = max(xmn - 1, 0), xhi = min(xmx + 1, GS - 1);

        for (int y = ylo; y <= yhi; ++y) {
            if ((cnt++ & 7) != w) continue;        // round-robin rows to waves
            int rb = bN + (z * GS + y) * GS;
            int st = __builtin_amdgcn_readfirstlane(cstart[rb + xlo]);
            int en = __builtin_amdgcn_readfirstlane(cstart[rb + xhi + 1]);
            #pragma unroll 4
            for (int k = st; k < en; ++k) {        // k wave-uniform -> s_load
                float4 c = ckey[k];
                float d = fmaf(c.x, qx, fmaf(c.y, qy, fmaf(c.z, qz, c.w)));
                INS3(d, k, e0, e1, e2, i0, i1, i2);
            }
        }
    }

    md[w][l][0] = e0; md[w][l][1] = e1; md[w][l][2] = e2;
    mi[w][l][0] = i0; mi[w][l][1] = i1; mi[w][l][2] = i2;
    __syncthreads();

    if (t < QPT) {
        float m0 = FINF, m1 = FINF, m2 = FINF;
        int   n0 = 0, n1 = 0, n2 = 0;
        #pragma unroll
        for (int ww = 0; ww < 8; ++ww) {
            INS3(md[ww][t][0], mi[ww][t][0], m0, m1, m2, n0, n1, n2);
            INS3(md[ww][t][1], mi[ww][t][1], m0, m1, m2, n0, n1, n2);
            INS3(md[ww][t][2], mi[ww][t][2], m0, m1, m2, n0, n1, n2);
        }
        // per-query margin: distance to own +-1-cell-box faces (grid-edge skipped)
        float mg = FINF;
        if (hx > 1)      mg = fminf(mg, qx - (GMIN + (hx - 1) * CS));
        if (hx < GS - 2) mg = fminf(mg, (GMIN + (hx + 2) * CS) - qx);
        if (hy > 1)      mg = fminf(mg, qy - (GMIN + (hy - 1) * CS));
        if (hy < GS - 2) mg = fminf(mg, (GMIN + (hy + 2) * CS) - qy);
        if (hz > 1)      mg = fminf(mg, qz - (GMIN + (hz - 1) * CS));
        if (hz < GS - 2) mg = fminf(mg, (GMIN + (hz + 2) * CS) - qz);
        if (m2 + qn <= mg * mg) {
            idw_write(qx, qy, qz, n0, n1, n2, ckey, cflow, out, b, origj);
        } else {
            int p = atomicAdd(&fbcnt[b], 1);
            fblist[b * NPTS + p] = ti * QPT + t;   // batch-local sorted position
        }
    }
}

// ---------------------------------------------------------------------------
// K5: wave-per-query fallback (R12-proven). Lane ln scans candidates
// ln, ln+64, ... (coalesced vector loads), butterfly shfl merge, lane 0
// writes. Worst-case grid, wave-uniform early exit.
// ---------------------------------------------------------------------------
__global__ __launch_bounds__(256) void fb_wave(
    const float4* __restrict__ qpos, const float4* __restrict__ ckey,
    const float4* __restrict__ cflow, const int* __restrict__ fbcnt,
    const int* __restrict__ fblist, float* __restrict__ out)
{
    int blk = blockIdx.x;                 // BATCH * NPTS/4 = 8192
    int b = blk >> 11, grp = blk & 2047;
    int t = (int)threadIdx.x;
    int w = t >> 6, ln = t & 63;
    int cnt = fbcnt[b];
    int idx = grp * 4 + w;
    if (idx >= cnt) return;               // wave-uniform exit

    int js = fblist[b * NPTS + idx];
    float4 qp = qpos[b * NPTS + js];
    float qx = qp.x, qy = qp.y, qz = qp.z;
    int origj = __float_as_int(qp.w);

    const float4* src = ckey + b * NPTS;

    float e0 = FINF, e1 = FINF, e2 = FINF;
    int   i0 = 0, i1 = 0, i2 = 0;
    #pragma unroll 4
    for (int k = ln; k < NPTS; k += 64) {
        float4 c = src[k];
        float d = fmaf(c.x, qx, fmaf(c.y, qy, fmaf(c.z, qz, c.w)));
        INS3(d, k, e0, e1, e2, i0, i1, i2);
    }
    #pragma unroll
    for (int o = 1; o < 64; o <<= 1) {
        float r0 = __shfl_xor(e0, o), r1 = __shfl_xor(e1, o), r2 = __shfl_xor(e2, o);
        int   s0 = __shfl_xor(i0, o), s1 = __shfl_xor(i1, o), s2 = __shfl_xor(i2, o);
        INS3(r0, s0, e0, e1, e2, i0, i1, i2);
        INS3(r1, s1, e0, e1, e2, i0, i1, i2);
        INS3(r2, s2, e0, e1, e2, i0, i1, i2);
    }
    if (ln == 0) {
        idw_write(qx, qy, qz, b * NPTS + i0, b * NPTS + i1, b * NPTS + i2,
                  ckey, cflow, out, b, origj);
    }
}

// ---------------------------------------------------------------------------
// Launcher. Workspace ~3.1 MB.
// ---------------------------------------------------------------------------
extern "C" void kernel_launch(void* const* d_in, const int* in_sizes, int n_in,
                              void* d_out, int out_size, void* d_ws, size_t ws_size,
                              hipStream_t stream)
{
    const float* xyz1  = (const float*)d_in[0];
    const float* xyz2  = (const float*)d_in[1];
    const float* flow1 = (const float*)d_in[2];
    float* out = (float*)d_out;

    char* p = (char*)d_ws;
    float4* ckey     = (float4*)p;  p += (size_t)BATCH * NPTS * 16;
    float4* cflow    = (float4*)p;  p += (size_t)BATCH * NPTS * 16;
    float4* qpos     = (float4*)p;  p += (size_t)BATCH * NPTS * 16;
    int*    counts_c = (int*)p;     p += (size_t)BATCH * NCP * 4;
    int*    counts_q = (int*)p;     p += (size_t)BATCH * NCP * 4;
    int*    fbcnt    = (int*)p;     p += 16;
    int*    cstart   = (int*)p;     p += ((size_t)BATCH * NCP + 4) * 4;
    int*    ccur     = (int*)p;     p += (size_t)BATCH * NCP * 4;
    int*    qstart   = (int*)p;     p += ((size_t)BATCH * NCP + 4) * 4;
    int*    qcur     = (int*)p;     p += (size_t)BATCH * NCP * 4;
    int*    fblist   = (int*)p;

    // zero counts_c + counts_q + fbcnt in one shot (contiguous)
    hipMemsetAsync(counts_c, 0, (size_t)BATCH * NCP * 4 * 2 + 16, stream);
    bin_both    <<<2 * BATCH * NPTS / 256, 256, 0, stream>>>(xyz1, xyz2, flow1, counts_c, counts_q);
    scan_chunks <<<8, 1024, 0, stream>>>(counts_c, cstart, ccur, counts_q, qstart, qcur);
    scatter_both<<<2 * BATCH * NPTS / 256, 256, 0, stream>>>(xyz1, xyz2, flow1, ccur, qcur, ckey, cflow, qpos);
    knn_tile    <<<BATCH * (NPTS / QPT), 512, 0, stream>>>(qpos, ckey, cflow, cstart, fbcnt, fblist, out);
    fb_wave     <<<BATCH * (NPTS / 4), 256, 0, stream>>>(qpos, ckey, cflow, fbcnt, fblist, out);
}